// Round 6
// baseline (141.538 us; speedup 1.0000x reference)
//
#include <hip/hip_runtime.h>

typedef __attribute__((ext_vector_type(4))) float f32x4;
typedef __attribute__((ext_vector_type(8))) short s16x8;
typedef unsigned short u16;

#define DEVI __device__ __forceinline__

// fp32 -> bf16 round-to-nearest-even
DEVI u16 f2bf(float f) {
    union { float f; unsigned int u; } v; v.f = f;
    unsigned int r = v.u + 0x7FFFu + ((v.u >> 16) & 1u);
    return (u16)(r >> 16);
}
DEVI float bf2f(u16 b) {
    union { unsigned int u; float f; } v; v.u = ((unsigned int)b) << 16;
    return v.f;
}

typedef __attribute__((address_space(1))) void gv_t;   // global
typedef __attribute__((address_space(3))) void sv_t;   // LDS

#define GLOAD16(SRC, DST) __builtin_amdgcn_global_load_lds( \
    (gv_t*)(SRC), (sv_t*)(DST), 16, 0, 0)

DEVI f32x4 mfma_bf16(s16x8 a, s16x8 b, f32x4 c) {
    return __builtin_amdgcn_mfma_f32_16x16x32_bf16(a, b, c, 0, 0, 0);
}

// ---------------------------------------------------------------------------
// fp32 -> bf16 conversion of x, wq, wk, wv, wo (one fused streaming pass)
// ---------------------------------------------------------------------------
__global__ void cvt_all_kernel(
    const float* __restrict__ x,  const float* __restrict__ wq, const float* __restrict__ wk,
    const float* __restrict__ wv, const float* __restrict__ wo,
    u16* __restrict__ xb, u16* __restrict__ wqb, u16* __restrict__ wkb,
    u16* __restrict__ wvb, u16* __restrict__ wob)
{
    int id = blockIdx.x * 256 + threadIdx.x;   // 0 .. 7372800-1 (f32x4 units)
    const float* s; u16* d; int off;
    if      (id < 737280)  { s = x;  d = xb;  off = id; }
    else if (id < 3686400) { s = wq; d = wqb; off = id - 737280; }
    else if (id < 4055040) { s = wk; d = wkb; off = id - 3686400; }
    else if (id < 4423680) { s = wv; d = wvb; off = id - 4055040; }
    else                   { s = wo; d = wob; off = id - 4423680; }
    f32x4 v = *(const f32x4*)(s + (size_t)off * 4);
    union { u16 u[4]; unsigned long long ll; } o;
    #pragma unroll
    for (int j = 0; j < 4; ++j) o.u[j] = f2bf(v[j]);
    *(unsigned long long*)(d + (size_t)off * 4) = o.ll;
}

// ---------------------------------------------------------------------------
// NT GEMM, split-K, 256x256 tile, depth-2 counted-vmcnt 2-phase pipeline.
// C_part[z] = A[M][K](bf16) * W[n][K](bf16)^T -> bf16 partials (no bias).
// BK=64, 512 threads = 8 waves of 128x64, 16x16x32 MFMA, gload_lds width 16,
// XOR chunk swizzle (proven 0-conflict). 128 KB LDS dbuf -> 1 block/CU.
// Per-wave tile 128x64 halves LDS-read bytes/FLOP vs 64x64: MFMA-dominant.
// XCD chunk map: 4 M-blocks of one N-stripe run consecutively per XCD.
// ---------------------------------------------------------------------------
__global__ __launch_bounds__(512, 2) void gemm256(
    const u16* __restrict__ A, int lda, int kit, int cpx,
    const u16* __restrict__ W0, int t0, int n0, int c0,
    const u16* __restrict__ W1, int t1, int n1, int c1,
    const u16* __restrict__ W2, int t2, int n2, int c2,
    u16* __restrict__ C, int ldc, long long cstride)
{
    __shared__ u16 Als[2][256 * 64];
    __shared__ u16 Bls[2][256 * 64];

    // XCD chunk mapping: gridDim.x = 8*cpx blocks per z-slice; XCD c gets
    // ords [c*cpx, (c+1)*cpx) = consecutive (N-tile, M-tile) pairs, M fastest.
    const int lin = blockIdx.x;
    const int ord = (lin & 7) * cpx + (lin >> 3);
    const int nbl = ord >> 2;        // N-tile (256 rows of W)
    const int yt  = ord & 3;         // M-tile (256 rows of A)

    const int tid  = threadIdx.x;
    const int lane = tid & 63;
    const int wid  = tid >> 6;          // 0..7
    const int li   = lane & 15;
    const int lg   = lane >> 4;
    const int m0   = yt * 256;

    const u16* W; int nt0, nsz, cb;
    if (nbl < t0)           { W = W0; nt0 = nbl * 256;             nsz = n0; cb = c0; }
    else if (nbl < t0 + t1) { W = W1; nt0 = (nbl - t0) * 256;      nsz = n1; cb = c1; }
    else                    { W = W2; nt0 = (nbl - t0 - t1) * 256; nsz = n2; cb = c2; }

    const int z  = blockIdx.z;
    const int S  = gridDim.z;
    const int it0 = (z * kit) / S;
    const int it1 = ((z + 1) * kit) / S;    // >= it0 + 12 for all uses here
    u16* Cp = C + (long long)z * cstride;

    const int wm = (wid >> 2) * 128;    // {0, 128}
    const int wn = (wid & 3) * 64;      // {0, 64, 128, 192}

    f32x4 acc[8][4];
    #pragma unroll
    for (int mi = 0; mi < 8; ++mi)
        #pragma unroll
        for (int ni = 0; ni < 4; ++ni)
            acc[mi][ni] = (f32x4){0.f, 0.f, 0.f, 0.f};

    // staging: 4 A-loads + 4 B-loads per thread per K-tile (16 B each).
    // load j covers LDS elems [ (j*512+tid)*8 .. +8 ): row = j*64 + tid/8.
#define STAGE(BUF, IT)                                                          \
    do {                                                                        \
        int k0_ = (IT) * 64;                                                    \
        _Pragma("unroll")                                                       \
        for (int j = 0; j < 4; ++j) {                                           \
            int g_   = j * 512 + tid;                                           \
            int row_ = g_ >> 3;                                                 \
            int cs_  = (tid & 7) ^ (row_ & 7);                                  \
            const u16* sa_ = A + (size_t)(m0 + row_) * lda + k0_ + cs_ * 8;     \
            GLOAD16(sa_, &Als[BUF][g_ * 8]);                                    \
        }                                                                       \
        _Pragma("unroll")                                                       \
        for (int j = 0; j < 4; ++j) {                                           \
            int g_   = j * 512 + tid;                                           \
            int row_ = g_ >> 3;                                                 \
            int wr_  = nt0 + row_;                                              \
            if (wr_ > nsz - 1) wr_ = nsz - 1;  /* ragged-N clamp */             \
            int cs_  = (tid & 7) ^ (row_ & 7);                                  \
            const u16* sb_ = W + (size_t)wr_ * lda + k0_ + cs_ * 8;             \
            GLOAD16(sb_, &Bls[BUF][g_ * 8]);                                    \
        }                                                                       \
    } while (0)

    STAGE(0, it0);
    asm volatile("" ::: "memory");     // keep the two stage groups ordered
    STAGE(1, it0 + 1);
    // outstanding per thread: 16 (8 for it0, 8 for it0+1)

    for (int it = it0; it < it1; ++it) {
        const int cur = (it - it0) & 1;

        if (it + 1 < it1) {
            // wait for tile `it`'s 8 loads only; next tile's 8 stay in flight
            asm volatile("s_waitcnt vmcnt(8)\n\ts_barrier" ::: "memory");
        } else {
            asm volatile("s_waitcnt vmcnt(0)\n\ts_barrier" ::: "memory");
        }

        // B fragments once (shared across all 8 M-frags)
        s16x8 bfv[4][2];
        #pragma unroll
        for (int ni = 0; ni < 4; ++ni)
            #pragma unroll
            for (int kc = 0; kc < 2; ++kc) {
                int row = wn + ni * 16 + li;
                int ch  = (kc * 4 + lg) ^ (row & 7);
                bfv[ni][kc] = *(const s16x8*)&Bls[cur][row * 64 + ch * 8];
            }
        __builtin_amdgcn_s_setprio(1);
        #pragma unroll
        for (int mi = 0; mi < 8; ++mi) {
            s16x8 af[2];
            #pragma unroll
            for (int kc = 0; kc < 2; ++kc) {
                int row = wm + mi * 16 + li;
                int ch  = (kc * 4 + lg) ^ (row & 7);
                af[kc] = *(const s16x8*)&Als[cur][row * 64 + ch * 8];
            }
            #pragma unroll
            for (int ni = 0; ni < 4; ++ni)
                #pragma unroll
                for (int kc = 0; kc < 2; ++kc)
                    acc[mi][ni] = mfma_bf16(af[kc], bfv[ni][kc], acc[mi][ni]);
        }
        __builtin_amdgcn_s_setprio(0);

        // my ds_reads complete, then barrier: block done reading buf[cur]
        // -> safe to restage it. vmcnt NOT drained here.
        asm volatile("s_waitcnt lgkmcnt(0)\n\ts_barrier" ::: "memory");

        if (it + 2 < it1) STAGE(cur, it + 2);
    }
#undef STAGE

    #pragma unroll
    for (int ni = 0; ni < 4; ++ni) {
        int colr = nt0 + wn + ni * 16 + li;
        if (colr < nsz) {
            #pragma unroll
            for (int mi = 0; mi < 8; ++mi)
                #pragma unroll
                for (int r = 0; r < 4; ++r) {
                    int row = m0 + wm + mi * 16 + lg * 4 + r;
                    Cp[(size_t)row * ldc + cb + colr] = f2bf(acc[mi][ni][r]);
                }
        }
    }
}

// ---------------------------------------------------------------------------
// RoPE + bias + bf16 convert from 3 bf16 split-K partials.
// ---------------------------------------------------------------------------
__global__ void rope_kernel(const u16* __restrict__ qkvp,
                            const float* __restrict__ qb, const float* __restrict__ kb,
                            const float* __restrict__ vb,
                            u16* __restrict__ qo, u16* __restrict__ ko, u16* __restrict__ vo)
{
    const long long PST = 1024LL * 5120;
    int id = blockIdx.x * 256 + threadIdx.x;   // 1024 * 2560
    int s  = id / 2560;
    int r  = id % 2560;
    const u16* r0 = qkvp + (size_t)s * 5120;
    if (r < 2304) {
        bool isq = r < 2048;
        int rr   = isq ? r : r - 2048;
        int hh   = rr >> 5;
        int d    = rr & 31;
        int col  = (isq ? 0 : 4096) + hh * 64 + d;
        int bcol = isq ? col : col - 4096;
        const float* bias = isq ? qb : kb;
        float t1 = bf2f(r0[col])      + bf2f(r0[col + PST])      + bf2f(r0[col + 2 * PST])      + bias[bcol];
        float t2 = bf2f(r0[col + 32]) + bf2f(r0[col + 32 + PST]) + bf2f(r0[col + 32 + 2 * PST]) + bias[bcol + 32];
        // inv_freq = 150000^(-d/32) = exp2(-d * log2(150000)/32)
        float ang = (float)s * exp2f((float)d * -0.5373314f);
        float sn, cs;
        sincosf(ang, &sn, &cs);
        float sc = isq ? 0.125f : 1.0f;    // fold score scale HD^-0.5 into q
        float o1 = (t1 * cs - t2 * sn) * sc;
        float o2 = (t1 * sn + t2 * cs) * sc;
        u16* dst = isq ? qo : ko;
        int ldd  = isq ? 4096 : 512;
        dst[(size_t)s * ldd + bcol]      = f2bf(o1);
        dst[(size_t)s * ldd + bcol + 32] = f2bf(o2);
    } else {
        int e = (r - 2304) * 2;
        int c0 = 4608 + e;
        float v0 = bf2f(r0[c0])     + bf2f(r0[c0 + PST])     + bf2f(r0[c0 + 2 * PST])     + vb[e];
        float v1 = bf2f(r0[c0 + 1]) + bf2f(r0[c0 + 1 + PST]) + bf2f(r0[c0 + 1 + 2 * PST]) + vb[e + 1];
        vo[(size_t)s * 512 + e]     = f2bf(v0);
        vo[(size_t)s * 512 + e + 1] = f2bf(v1);
    }
}

// ---------------------------------------------------------------------------
// out = sum of 5 bf16 split-K partials + bias (fp32)
// ---------------------------------------------------------------------------
__global__ void reduce_out_kernel(const u16* __restrict__ parts,
                                  const float* __restrict__ bias,
                                  float* __restrict__ out)
{
    int id = blockIdx.x * 256 + threadIdx.x;      // 0..368639 (8-elem groups)
    const long long stride = 1024LL * 2880;
    long long base = (long long)id * 8;
    float s[8];
    #pragma unroll
    for (int j = 0; j < 8; ++j) s[j] = 0.f;
    #pragma unroll
    for (int p = 0; p < 5; ++p) {
        s16x8 v = *(const s16x8*)(parts + p * stride + base);
        #pragma unroll
        for (int j = 0; j < 8; ++j) s[j] += bf2f((u16)v[j]);
    }
    int cb = (int)(base % 2880);
    f32x4 b0 = *(const f32x4*)(bias + cb);
    f32x4 b1 = *(const f32x4*)(bias + cb + 4);
    f32x4 o0 = {s[0] + b0[0], s[1] + b0[1], s[2] + b0[2], s[3] + b0[3]};
    f32x4 o1 = {s[4] + b1[0], s[5] + b1[1], s[6] + b1[2], s[7] + b1[3]};
    *(f32x4*)(out + base)     = o0;
    *(f32x4*)(out + base + 4) = o1;
}

// ---------------------------------------------------------------------------
// Sliding-window GQA attention with sinks (unchanged, proven).
// ---------------------------------------------------------------------------
__global__ __launch_bounds__(256, 2) void attn_kernel(
    const u16* __restrict__ Q, const u16* __restrict__ Kb, const u16* __restrict__ Vb,
    const float* __restrict__ sinks, u16* __restrict__ Ob)
{
    __shared__ u16 Kls[64 * 64];
    __shared__ u16 Pls[4][16 * 72];

    const int h    = blockIdx.x;
    const int qblk = blockIdx.y;
    const int kvh  = h >> 3;
    const int tid  = threadIdx.x;
    const int lane = tid & 63;
    const int w    = tid >> 6;
    const int li   = lane & 15;
    const int lg   = lane >> 4;
    const int qw   = qblk * 64 + w * 16;

    s16x8 aq[2];
    {
        const u16* qrow = Q + ((size_t)(qw + li) * 64 + h) * 64 + lg * 8;
        aq[0] = *(const s16x8*)(qrow);
        aq[1] = *(const s16x8*)(qrow + 32);
    }

    const float snk = sinks[h];
    float m_run[4], l_run[4];
    f32x4 oacc[4];
    #pragma unroll
    for (int r = 0; r < 4; ++r) { m_run[r] = snk; l_run[r] = 1.0f; }
    #pragma unroll
    for (int ni = 0; ni < 4; ++ni) oacc[ni] = (f32x4){0.f, 0.f, 0.f, 0.f};

    const int srow = tid >> 3;
    const int slc  = (tid & 7) ^ (srow & 7);

    for (int t = 0; t < 3; ++t) {
        int jt = qblk - 2 + t;
        if (jt < 0) continue;
        int j0 = jt * 64;

        #pragma unroll
        for (int it = 0; it < 2; ++it) {
            const u16* src = Kb + ((size_t)(j0 + it * 32 + srow) * 8 + kvh) * 64 + slc * 8;
            GLOAD16(src, &Kls[(it * 256 + w * 64) * 8]);
        }
        __syncthreads();

        f32x4 sc[4];
        #pragma unroll
        for (int nf = 0; nf < 4; ++nf) {
            sc[nf] = (f32x4){0.f, 0.f, 0.f, 0.f};
            #pragma unroll
            for (int kc = 0; kc < 2; ++kc) {
                int row = nf * 16 + li;
                int ch  = (kc * 4 + lg) ^ (row & 7);
                s16x8 bk = *(const s16x8*)&Kls[row * 64 + ch * 8];
                sc[nf] = mfma_bf16(aq[kc], bk, sc[nf]);
            }
        }

        #pragma unroll
        for (int r = 0; r < 4; ++r) {
            const int qg = qw + lg * 4 + r;
            float mx = -1e30f;
            #pragma unroll
            for (int nf = 0; nf < 4; ++nf) {
                int jg = j0 + nf * 16 + li;
                bool ok = (jg <= qg) && (qg - jg < 128);
                float v = ok ? sc[nf][r] : -1e30f;
                sc[nf][r] = v;
                mx = fmaxf(mx, v);
            }
            #pragma unroll
            for (int off = 1; off < 16; off <<= 1)
                mx = fmaxf(mx, __shfl_xor(mx, off));
            float mnew = fmaxf(m_run[r], mx);
            float corr = __expf(m_run[r] - mnew);
            m_run[r] = mnew;
            float rs = 0.f;
            #pragma unroll
            for (int nf = 0; nf < 4; ++nf) {
                float p = __expf(sc[nf][r] - mnew);
                rs += p;
                Pls[w][(lg * 4 + r) * 72 + nf * 16 + li] = f2bf(p);
            }
            #pragma unroll
            for (int off = 1; off < 16; off <<= 1)
                rs += __shfl_xor(rs, off);
            l_run[r] = l_run[r] * corr + rs;
            #pragma unroll
            for (int ni = 0; ni < 4; ++ni) oacc[ni][r] *= corr;
        }
        __syncthreads();   // all K reads done; P writes drained

        #pragma unroll
        for (int kc = 0; kc < 2; ++kc) {
            s16x8 pa = *(const s16x8*)&Pls[w][li * 72 + kc * 32 + lg * 8];
            #pragma unroll
            for (int ni = 0; ni < 4; ++ni) {
                const u16* vsrc = Vb + ((size_t)(j0 + kc * 32 + lg * 8) * 8 + kvh) * 64 + ni * 16 + li;
                s16x8 bv;
                #pragma unroll
                for (int i = 0; i < 8; ++i) bv[i] = (short)vsrc[(size_t)i * 512];
                oacc[ni] = mfma_bf16(pa, bv, oacc[ni]);
            }
        }
    }

    #pragma unroll
    for (int r = 0; r < 4; ++r) {
        float inv = 1.0f / l_run[r];
        #pragma unroll
        for (int ni = 0; ni < 4; ++ni)
            Ob[((size_t)(qw + lg * 4 + r) * 64 + h) * 64 + ni * 16 + li] = f2bf(oacc[ni][r] * inv);
    }
}

// ---------------------------------------------------------------------------
extern "C" void kernel_launch(void* const* d_in, const int* in_sizes, int n_in,
                              void* d_out, int out_size, void* d_ws, size_t ws_size,
                              hipStream_t stream)
{
    const float* x     = (const float*)d_in[0];
    const float* wq_w  = (const float*)d_in[1];
    const float* wq_b  = (const float*)d_in[2];
    const float* wk_w  = (const float*)d_in[3];
    const float* wk_b  = (const float*)d_in[4];
    const float* wv_w  = (const float*)d_in[5];
    const float* wv_b  = (const float*)d_in[6];
    const float* wo_w  = (const float*)d_in[7];
    const float* wo_b  = (const float*)d_in[8];
    const float* sinks = (const float*)d_in[9];

    char* ws = (char*)d_ws;
    // Layout (peak 112.1 MB; 117.9 proven available):
    //   [0, 35,389,440)           xb|wqb|wkb|wvb        (cvt -> gemm1)
    //       after rope overlays:  qr@0|kr|vbf|attb      (rope -> gemm2)
    //   [35,389,440, 66,846,720)  qkvp 3 bf16 partials  (gemm1 -> rope)
    //   [58,982,400, 88,473,600)  oprt 5 bf16 partials  (gemm2 -> reduce)
    //       (overlaps dead qkvp tail -- qkvp dead after rope)
    //   [88,473,600, 112,066,560) wob                   (cvt -> gemm2)
    u16*   xb   = (u16*)(ws + 0);
    u16*   wqb  = (u16*)(ws + 5898240ULL);
    u16*   wkb  = (u16*)(ws + 29491200ULL);
    u16*   wvb  = (u16*)(ws + 32440320ULL);
    u16*   qkvp = (u16*)(ws + 35389440ULL);      // 3 bf16 partials, stride 1024*5120
    u16*   qr   = (u16*)(ws + 0);
    u16*   kr   = (u16*)(ws + 8388608ULL);
    u16*   vbf  = (u16*)(ws + 9437184ULL);
    u16*   attb = (u16*)(ws + 10485760ULL);
    u16*   oprt = (u16*)(ws + 58982400ULL);      // 5 bf16 partials, stride 1024*2880
    u16*   wob  = (u16*)(ws + 88473600ULL);

    (void)in_sizes; (void)n_in; (void)out_size; (void)ws_size;

    // 1) bf16 conversions (x, wq, wk, wv, wo -- one pass)
    cvt_all_kernel<<<28800, 256, 0, stream>>>(x, wq_w, wk_w, wv_w, wo_w,
                                              xb, wqb, wkb, wvb, wob);
    // 2) fused QKV projection, split-K=3 -> 3 bf16 partials [1024][5120]
    //    tiles: 20 N (16 q + 2 k + 2 v, all 256-aligned) x 4 M = 80 blocks/z
    gemm256<<<dim3(80, 1, 3), 512, 0, stream>>>(xb, 2880, 45, 10,
        wqb, 16, 4096, 0,
        wkb, 2, 512, 4096,
        wvb, 2, 512, 4608,
        qkvp, 5120, 1024LL * 5120);
    // 3) RoPE + partial-sum + bias + convert (q pre-scaled by 0.125)
    rope_kernel<<<10240, 256, 0, stream>>>(qkvp, wq_b, wk_b, wv_b, qr, kr, vbf);
    // 4) attention -> attb bf16 [1024][4096]
    attn_kernel<<<dim3(64, 16), 256, 0, stream>>>(qr, kr, vbf, sinks, attb);
    // 5) output projection, split-K=5 -> 5 bf16 partials [1024][2880]
    //    tiles: 12 N (last ragged: 64 valid cols) x 4 M = 48 blocks/z
    gemm256<<<dim3(48, 1, 5), 512, 0, stream>>>(attb, 4096, 64, 6,
        wob, 12, 2880, 0,
        wob, 0, 0, 0,
        wob, 0, 0, 0,
        oprt, 2880, 1024LL * 2880);
    // 6) reduce partials + bias -> d_out fp32 [1024][2880]
    reduce_out_kernel<<<1440, 256, 0, stream>>>(oprt, wo_b, (float*)d_out);
}

// Round 7
// 139.023 us; speedup vs baseline: 1.0181x; 1.0181x over previous
//
#include <hip/hip_runtime.h>

typedef __attribute__((ext_vector_type(4))) float f32x4;
typedef __attribute__((ext_vector_type(8))) short s16x8;
typedef unsigned short u16;

#define DEVI __device__ __forceinline__

// fp32 -> bf16 round-to-nearest-even
DEVI u16 f2bf(float f) {
    union { float f; unsigned int u; } v; v.f = f;
    unsigned int r = v.u + 0x7FFFu + ((v.u >> 16) & 1u);
    return (u16)(r >> 16);
}
DEVI float bf2f(u16 b) {
    union { unsigned int u; float f; } v; v.u = ((unsigned int)b) << 16;
    return v.f;
}

typedef __attribute__((address_space(1))) void gv_t;   // global
typedef __attribute__((address_space(3))) void sv_t;   // LDS

#define GLOAD16(SRC, DST) __builtin_amdgcn_global_load_lds( \
    (gv_t*)(SRC), (sv_t*)(DST), 16, 0, 0)

DEVI f32x4 mfma_bf16(s16x8 a, s16x8 b, f32x4 c) {
    return __builtin_amdgcn_mfma_f32_16x16x32_bf16(a, b, c, 0, 0, 0);
}

// ---------------------------------------------------------------------------
// fp32 -> bf16 conversion of x, wq, wk, wv, wo (one fused streaming pass)
// ---------------------------------------------------------------------------
__global__ void cvt_all_kernel(
    const float* __restrict__ x,  const float* __restrict__ wq, const float* __restrict__ wk,
    const float* __restrict__ wv, const float* __restrict__ wo,
    u16* __restrict__ xb, u16* __restrict__ wqb, u16* __restrict__ wkb,
    u16* __restrict__ wvb, u16* __restrict__ wob)
{
    int id = blockIdx.x * 256 + threadIdx.x;   // 0 .. 7372800-1 (f32x4 units)
    const float* s; u16* d; int off;
    if      (id < 737280)  { s = x;  d = xb;  off = id; }
    else if (id < 3686400) { s = wq; d = wqb; off = id - 737280; }
    else if (id < 4055040) { s = wk; d = wkb; off = id - 3686400; }
    else if (id < 4423680) { s = wv; d = wvb; off = id - 4055040; }
    else                   { s = wo; d = wob; off = id - 4423680; }
    f32x4 v = *(const f32x4*)(s + (size_t)off * 4);
    union { u16 u[4]; unsigned long long ll; } o;
    #pragma unroll
    for (int j = 0; j < 4; ++j) o.u[j] = f2bf(v[j]);
    *(unsigned long long*)(d + (size_t)off * 4) = o.ll;
}

// ---------------------------------------------------------------------------
// NT GEMM, split-K, 256x256 tile, 8-PHASE schedule (m201 template).
// C_part[z] = A[M][K](bf16) * W[n][K](bf16)^T -> bf16 partials (no bias).
// BK=64, 512 threads = 8 waves (2M x 4N). Per main-loop iter: 2 K-tiles,
// 8 phases; each phase = one 128x128 block-quadrant x K=64:
//   { 12 ds_read_b128 ; stage 1 half-tile (2 gload_lds) ; [vmcnt] ;
//     s_barrier ; setprio(1) ; 16 MFMA ; setprio(0) ; s_barrier }
// Half-tile staging fills LDS slots exactly after their last quadrant read:
//   ph1:A1(t+1) ph2:B1(t+1) ph3:A0(t+2) ph4:B0(t+2)+vmcnt(4)
//   ph5:A1(t+2) ph6:B1(t+2) ph7:A0(t+3) ph8:B0(t+3)+vmcnt(4)
// vmcnt never drains to 0 in steady state (2 half-tiles in flight).
// XOR chunk swizzle both sides (0 bank conflicts, proven R1-R6).
// ---------------------------------------------------------------------------
__global__ __launch_bounds__(512, 2) void gemm8p(
    const u16* __restrict__ A, int lda, int kit, int cpx,
    const u16* __restrict__ W0, int t0, int n0, int c0,
    const u16* __restrict__ W1, int t1, int n1, int c1,
    const u16* __restrict__ W2, int t2, int n2, int c2,
    u16* __restrict__ C, int ldc, long long cstride)
{
    __shared__ u16 Als[2][256 * 64];
    __shared__ u16 Bls[2][256 * 64];

    // XCD chunk mapping: bijective; XCD c gets cpx consecutive ords.
    const int lin = blockIdx.x;
    const int ord = (lin & 7) * cpx + (lin >> 3);
    const int nbl = ord >> 2;        // N-tile (256 cols)
    const int yt  = ord & 3;         // M-tile (256 rows)

    const int tid  = threadIdx.x;
    const int lane = tid & 63;
    const int wid  = tid >> 6;          // 0..7
    const int li   = lane & 15;
    const int lg   = lane >> 4;
    const int m0   = yt * 256;
    const int wr   = wid >> 2;          // 0..1  (M)
    const int wc   = wid & 3;           // 0..3  (N)

    const u16* W; int nt0, nsz, cb;
    if (nbl < t0)           { W = W0; nt0 = nbl * 256;             nsz = n0; cb = c0; }
    else if (nbl < t0 + t1) { W = W1; nt0 = (nbl - t0) * 256;      nsz = n1; cb = c1; }
    else                    { W = W2; nt0 = (nbl - t0 - t1) * 256; nsz = n2; cb = c2; }

    const int z  = blockIdx.z;
    const int S  = gridDim.z;
    const int it0 = (z * kit) / S;
    const int it1 = ((z + 1) * kit) / S;
    u16* Cp = C + (long long)z * cstride;

    f32x4 acc[2][2][4][2];
    #pragma unroll
    for (int qm = 0; qm < 2; ++qm)
        #pragma unroll
        for (int qn = 0; qn < 2; ++qn)
            #pragma unroll
            for (int mi = 0; mi < 4; ++mi)
                #pragma unroll
                for (int ni = 0; ni < 2; ++ni)
                    acc[qm][qn][mi][ni] = (f32x4){0.f, 0.f, 0.f, 0.f};

    // Stage one half-tile (128 rows x 64 cols, 16 KB): 2 gload_lds / thread.
    // LDS linear dest; global source inverse-swizzled (chunk ^= row&7).
    auto stage_half = [&](int isB, int tile, int h) {
        if (tile >= it1) return;
        const int k0 = tile * 64;
        const int buf = tile & 1;
        #pragma unroll
        for (int j = 0; j < 2; ++j) {
            int g  = j * 512 + tid;        // chunk slot 0..1023 within half
            int lr = g >> 3;               // 0..127 local row
            int c8 = g & 7;
            int row = h * 128 + lr;
            int sc  = c8 ^ (lr & 7);       // inverse swizzle (row&7 == lr&7)
            if (isB) {
                int wrow = nt0 + row; if (wrow > nsz - 1) wrow = nsz - 1;
                GLOAD16(W + (size_t)wrow * lda + k0 + sc * 8,
                        &Bls[buf][row * 64 + c8 * 8]);
            } else {
                GLOAD16(A + (size_t)(m0 + row) * lda + k0 + sc * 8,
                        &Als[buf][row * 64 + c8 * 8]);
            }
        }
    };

    // One phase: quadrant (QM,QN) of TILE; stage (SISB, STILE, SH); VM: -1
    // none, 4 -> vmcnt(4), 0 -> vmcnt(0). All ds_reads precede the barrier;
    // each wave's reads complete before its MFMA (register deps), hence
    // before the phase-end barrier -> staging into dead slots is race-free.
#define PHASE(TILE, QM, QN, SISB, STILE, SH, VM)                               \
    do {                                                                       \
        const int buf_ = (TILE) & 1;                                           \
        s16x8 af_[4][2], bf_[2][2];                                            \
        _Pragma("unroll")                                                      \
        for (int mi = 0; mi < 4; ++mi)                                         \
            _Pragma("unroll")                                                  \
            for (int kc = 0; kc < 2; ++kc) {                                   \
                int row = (QM) * 128 + wr * 64 + mi * 16 + li;                 \
                int ch  = (kc * 4 + lg) ^ (row & 7);                           \
                af_[mi][kc] = *(const s16x8*)&Als[buf_][row * 64 + ch * 8];    \
            }                                                                  \
        _Pragma("unroll")                                                      \
        for (int ni = 0; ni < 2; ++ni)                                         \
            _Pragma("unroll")                                                  \
            for (int kc = 0; kc < 2; ++kc) {                                   \
                int row = (QN) * 128 + wc * 32 + ni * 16 + li;                 \
                int ch  = (kc * 4 + lg) ^ (row & 7);                           \
                bf_[ni][kc] = *(const s16x8*)&Bls[buf_][row * 64 + ch * 8];    \
            }                                                                  \
        stage_half((SISB), (STILE), (SH));                                     \
        {                                                                      \
            int vm_ = (VM);                                                    \
            if (vm_ == 4)      asm volatile("s_waitcnt vmcnt(4)" ::: "memory");\
            else if (vm_ == 0) asm volatile("s_waitcnt vmcnt(0)" ::: "memory");\
        }                                                                      \
        asm volatile("s_barrier" ::: "memory");                                \
        __builtin_amdgcn_s_setprio(1);                                         \
        _Pragma("unroll")                                                      \
        for (int mi = 0; mi < 4; ++mi)                                         \
            _Pragma("unroll")                                                  \
            for (int ni = 0; ni < 2; ++ni)                                     \
                _Pragma("unroll")                                              \
                for (int kc = 0; kc < 2; ++kc)                                 \
                    acc[QM][QN][mi][ni] =                                      \
                        mfma_bf16(af_[mi][kc], bf_[ni][kc], acc[QM][QN][mi][ni]); \
        __builtin_amdgcn_s_setprio(0);                                         \
        asm volatile("s_barrier" ::: "memory");                                \
    } while (0)

    // Prologue: tile it0 complete + A0,B0(it0+1) in flight (steady invariant).
    stage_half(0, it0, 0);         // A0(t0)
    stage_half(1, it0, 0);         // B0(t0)
    stage_half(0, it0, 1);         // A1(t0)
    stage_half(1, it0, 1);         // B1(t0)
    stage_half(0, it0 + 1, 0);     // A0(t0+1)
    stage_half(1, it0 + 1, 0);     // B0(t0+1)
    asm volatile("s_waitcnt vmcnt(4)" ::: "memory");
    asm volatile("s_barrier" ::: "memory");

    int t = it0;
    for (; t + 1 < it1; t += 2) {
        PHASE(t,     0, 0, 0, t + 1, 1, -1);                    // st A1(t+1)
        PHASE(t,     0, 1, 1, t + 1, 1, -1);                    // st B1(t+1)
        PHASE(t,     1, 0, 0, t + 2, 0, -1);                    // st A0(t+2)
        PHASE(t,     1, 1, 1, t + 2, 0, (t + 2 < it1) ? 4 : 0); // st B0(t+2)
        PHASE(t + 1, 0, 0, 0, t + 2, 1, -1);                    // st A1(t+2)
        PHASE(t + 1, 0, 1, 1, t + 2, 1, -1);                    // st B1(t+2)
        PHASE(t + 1, 1, 0, 0, t + 3, 0, -1);                    // st A0(t+3)
        PHASE(t + 1, 1, 1, 1, t + 3, 0, 4);                     // st B0(t+3)
    }
    if (t < it1) {   // odd-count tail tile (fully staged by last iter)
        PHASE(t, 0, 0, 0, it1, 0, 0);    // drain: confirms A1,B1(t)
        PHASE(t, 0, 1, 0, it1, 0, -1);
        PHASE(t, 1, 0, 0, it1, 0, -1);
        PHASE(t, 1, 1, 0, it1, 0, -1);
    }
#undef PHASE

    #pragma unroll
    for (int qn = 0; qn < 2; ++qn)
        #pragma unroll
        for (int ni = 0; ni < 2; ++ni) {
            int colr = nt0 + qn * 128 + wc * 32 + ni * 16 + li;
            if (colr < nsz) {
                #pragma unroll
                for (int qm = 0; qm < 2; ++qm)
                    #pragma unroll
                    for (int mi = 0; mi < 4; ++mi)
                        #pragma unroll
                        for (int r = 0; r < 4; ++r) {
                            int row = m0 + qm * 128 + wr * 64 + mi * 16 + lg * 4 + r;
                            Cp[(size_t)row * ldc + cb + colr] =
                                f2bf(acc[qm][qn][mi][ni][r]);
                        }
            }
        }
}

// ---------------------------------------------------------------------------
// RoPE + bias + bf16 convert from 3 bf16 split-K partials.
// ---------------------------------------------------------------------------
__global__ void rope_kernel(const u16* __restrict__ qkvp,
                            const float* __restrict__ qb, const float* __restrict__ kb,
                            const float* __restrict__ vb,
                            u16* __restrict__ qo, u16* __restrict__ ko, u16* __restrict__ vo)
{
    const long long PST = 1024LL * 5120;
    int id = blockIdx.x * 256 + threadIdx.x;   // 1024 * 2560
    int s  = id / 2560;
    int r  = id % 2560;
    const u16* r0 = qkvp + (size_t)s * 5120;
    if (r < 2304) {
        bool isq = r < 2048;
        int rr   = isq ? r : r - 2048;
        int hh   = rr >> 5;
        int d    = rr & 31;
        int col  = (isq ? 0 : 4096) + hh * 64 + d;
        int bcol = isq ? col : col - 4096;
        const float* bias = isq ? qb : kb;
        float t1 = bf2f(r0[col])      + bf2f(r0[col + PST])      + bf2f(r0[col + 2 * PST])      + bias[bcol];
        float t2 = bf2f(r0[col + 32]) + bf2f(r0[col + 32 + PST]) + bf2f(r0[col + 32 + 2 * PST]) + bias[bcol + 32];
        // inv_freq = 150000^(-d/32) = exp2(-d * log2(150000)/32)
        float ang = (float)s * exp2f((float)d * -0.5373314f);
        float sn, cs;
        sincosf(ang, &sn, &cs);
        float sc = isq ? 0.125f : 1.0f;    // fold score scale HD^-0.5 into q
        float o1 = (t1 * cs - t2 * sn) * sc;
        float o2 = (t1 * sn + t2 * cs) * sc;
        u16* dst = isq ? qo : ko;
        int ldd  = isq ? 4096 : 512;
        dst[(size_t)s * ldd + bcol]      = f2bf(o1);
        dst[(size_t)s * ldd + bcol + 32] = f2bf(o2);
    } else {
        int e = (r - 2304) * 2;
        int c0 = 4608 + e;
        float v0 = bf2f(r0[c0])     + bf2f(r0[c0 + PST])     + bf2f(r0[c0 + 2 * PST])     + vb[e];
        float v1 = bf2f(r0[c0 + 1]) + bf2f(r0[c0 + 1 + PST]) + bf2f(r0[c0 + 1 + 2 * PST]) + vb[e + 1];
        vo[(size_t)s * 512 + e]     = f2bf(v0);
        vo[(size_t)s * 512 + e + 1] = f2bf(v1);
    }
}

// ---------------------------------------------------------------------------
// out = sum of 5 bf16 split-K partials + bias (fp32)
// ---------------------------------------------------------------------------
__global__ void reduce_out_kernel(const u16* __restrict__ parts,
                                  const float* __restrict__ bias,
                                  float* __restrict__ out)
{
    int id = blockIdx.x * 256 + threadIdx.x;      // 0..368639 (8-elem groups)
    const long long stride = 1024LL * 2880;
    long long base = (long long)id * 8;
    float s[8];
    #pragma unroll
    for (int j = 0; j < 8; ++j) s[j] = 0.f;
    #pragma unroll
    for (int p = 0; p < 5; ++p) {
        s16x8 v = *(const s16x8*)(parts + p * stride + base);
        #pragma unroll
        for (int j = 0; j < 8; ++j) s[j] += bf2f((u16)v[j]);
    }
    int cb = (int)(base % 2880);
    f32x4 b0 = *(const f32x4*)(bias + cb);
    f32x4 b1 = *(const f32x4*)(bias + cb + 4);
    f32x4 o0 = {s[0] + b0[0], s[1] + b0[1], s[2] + b0[2], s[3] + b0[3]};
    f32x4 o1 = {s[4] + b1[0], s[5] + b1[1], s[6] + b1[2], s[7] + b1[3]};
    *(f32x4*)(out + base)     = o0;
    *(f32x4*)(out + base + 4) = o1;
}

// ---------------------------------------------------------------------------
// Sliding-window GQA attention with sinks (unchanged, proven).
// ---------------------------------------------------------------------------
__global__ __launch_bounds__(256, 2) void attn_kernel(
    const u16* __restrict__ Q, const u16* __restrict__ Kb, const u16* __restrict__ Vb,
    const float* __restrict__ sinks, u16* __restrict__ Ob)
{
    __shared__ u16 Kls[64 * 64];
    __shared__ u16 Pls[4][16 * 72];

    const int h    = blockIdx.x;
    const int qblk = blockIdx.y;
    const int kvh  = h >> 3;
    const int tid  = threadIdx.x;
    const int lane = tid & 63;
    const int w    = tid >> 6;
    const int li   = lane & 15;
    const int lg   = lane >> 4;
    const int qw   = qblk * 64 + w * 16;

    s16x8 aq[2];
    {
        const u16* qrow = Q + ((size_t)(qw + li) * 64 + h) * 64 + lg * 8;
        aq[0] = *(const s16x8*)(qrow);
        aq[1] = *(const s16x8*)(qrow + 32);
    }

    const float snk = sinks[h];
    float m_run[4], l_run[4];
    f32x4 oacc[4];
    #pragma unroll
    for (int r = 0; r < 4; ++r) { m_run[r] = snk; l_run[r] = 1.0f; }
    #pragma unroll
    for (int ni = 0; ni < 4; ++ni) oacc[ni] = (f32x4){0.f, 0.f, 0.f, 0.f};

    const int srow = tid >> 3;
    const int slc  = (tid & 7) ^ (srow & 7);

    for (int t = 0; t < 3; ++t) {
        int jt = qblk - 2 + t;
        if (jt < 0) continue;
        int j0 = jt * 64;

        #pragma unroll
        for (int it = 0; it < 2; ++it) {
            const u16* src = Kb + ((size_t)(j0 + it * 32 + srow) * 8 + kvh) * 64 + slc * 8;
            GLOAD16(src, &Kls[(it * 256 + w * 64) * 8]);
        }
        __syncthreads();

        f32x4 sc[4];
        #pragma unroll
        for (int nf = 0; nf < 4; ++nf) {
            sc[nf] = (f32x4){0.f, 0.f, 0.f, 0.f};
            #pragma unroll
            for (int kc = 0; kc < 2; ++kc) {
                int row = nf * 16 + li;
                int ch  = (kc * 4 + lg) ^ (row & 7);
                s16x8 bk = *(const s16x8*)&Kls[row * 64 + ch * 8];
                sc[nf] = mfma_bf16(aq[kc], bk, sc[nf]);
            }
        }

        #pragma unroll
        for (int r = 0; r < 4; ++r) {
            const int qg = qw + lg * 4 + r;
            float mx = -1e30f;
            #pragma unroll
            for (int nf = 0; nf < 4; ++nf) {
                int jg = j0 + nf * 16 + li;
                bool ok = (jg <= qg) && (qg - jg < 128);
                float v = ok ? sc[nf][r] : -1e30f;
                sc[nf][r] = v;
                mx = fmaxf(mx, v);
            }
            #pragma unroll
            for (int off = 1; off < 16; off <<= 1)
                mx = fmaxf(mx, __shfl_xor(mx, off));
            float mnew = fmaxf(m_run[r], mx);
            float corr = __expf(m_run[r] - mnew);
            m_run[r] = mnew;
            float rs = 0.f;
            #pragma unroll
            for (int nf = 0; nf < 4; ++nf) {
                float p = __expf(sc[nf][r] - mnew);
                rs += p;
                Pls[w][(lg * 4 + r) * 72 + nf * 16 + li] = f2bf(p);
            }
            #pragma unroll
            for (int off = 1; off < 16; off <<= 1)
                rs += __shfl_xor(rs, off);
            l_run[r] = l_run[r] * corr + rs;
            #pragma unroll
            for (int ni = 0; ni < 4; ++ni) oacc[ni][r] *= corr;
        }
        __syncthreads();   // all K reads done; P writes drained

        #pragma unroll
        for (int kc = 0; kc < 2; ++kc) {
            s16x8 pa = *(const s16x8*)&Pls[w][li * 72 + kc * 32 + lg * 8];
            #pragma unroll
            for (int ni = 0; ni < 4; ++ni) {
                const u16* vsrc = Vb + ((size_t)(j0 + kc * 32 + lg * 8) * 8 + kvh) * 64 + ni * 16 + li;
                s16x8 bv;
                #pragma unroll
                for (int i = 0; i < 8; ++i) bv[i] = (short)vsrc[(size_t)i * 512];
                oacc[ni] = mfma_bf16(pa, bv, oacc[ni]);
            }
        }
    }

    #pragma unroll
    for (int r = 0; r < 4; ++r) {
        float inv = 1.0f / l_run[r];
        #pragma unroll
        for (int ni = 0; ni < 4; ++ni)
            Ob[((size_t)(qw + lg * 4 + r) * 64 + h) * 64 + ni * 16 + li] = f2bf(oacc[ni][r] * inv);
    }
}

// ---------------------------------------------------------------------------
extern "C" void kernel_launch(void* const* d_in, const int* in_sizes, int n_in,
                              void* d_out, int out_size, void* d_ws, size_t ws_size,
                              hipStream_t stream)
{
    const float* x     = (const float*)d_in[0];
    const float* wq_w  = (const float*)d_in[1];
    const float* wq_b  = (const float*)d_in[2];
    const float* wk_w  = (const float*)d_in[3];
    const float* wk_b  = (const float*)d_in[4];
    const float* wv_w  = (const float*)d_in[5];
    const float* wv_b  = (const float*)d_in[6];
    const float* wo_w  = (const float*)d_in[7];
    const float* wo_b  = (const float*)d_in[8];
    const float* sinks = (const float*)d_in[9];

    char* ws = (char*)d_ws;
    // Layout (peak 112.1 MB; 117.9 proven available):
    //   [0, 35,389,440)           xb|wqb|wkb|wvb        (cvt -> gemm1)
    //       after rope overlays:  qr@0|kr|vbf|attb      (rope -> gemm2)
    //   [35,389,440, 66,846,720)  qkvp 3 bf16 partials  (gemm1 -> rope)
    //   [58,982,400, 88,473,600)  oprt 5 bf16 partials  (gemm2 -> reduce)
    //       (overlaps dead qkvp tail -- qkvp dead after rope)
    //   [88,473,600, 112,066,560) wob                   (cvt -> gemm2)
    u16*   xb   = (u16*)(ws + 0);
    u16*   wqb  = (u16*)(ws + 5898240ULL);
    u16*   wkb  = (u16*)(ws + 29491200ULL);
    u16*   wvb  = (u16*)(ws + 32440320ULL);
    u16*   qkvp = (u16*)(ws + 35389440ULL);      // 3 bf16 partials, stride 1024*5120
    u16*   qr   = (u16*)(ws + 0);
    u16*   kr   = (u16*)(ws + 8388608ULL);
    u16*   vbf  = (u16*)(ws + 9437184ULL);
    u16*   attb = (u16*)(ws + 10485760ULL);
    u16*   oprt = (u16*)(ws + 58982400ULL);      // 5 bf16 partials, stride 1024*2880
    u16*   wob  = (u16*)(ws + 88473600ULL);

    (void)in_sizes; (void)n_in; (void)out_size; (void)ws_size;

    // 1) bf16 conversions (x, wq, wk, wv, wo -- one pass)
    cvt_all_kernel<<<28800, 256, 0, stream>>>(x, wq_w, wk_w, wv_w, wo_w,
                                              xb, wqb, wkb, wvb, wob);
    // 2) fused QKV projection, split-K=3 -> 3 bf16 partials [1024][5120]
    //    tiles: 20 N (16 q + 2 k + 2 v, all 256-aligned) x 4 M = 80 blocks/z
    gemm8p<<<dim3(80, 1, 3), 512, 0, stream>>>(xb, 2880, 45, 10,
        wqb, 16, 4096, 0,
        wkb, 2, 512, 4096,
        wvb, 2, 512, 4608,
        qkvp, 5120, 1024LL * 5120);
    // 3) RoPE + partial-sum + bias + convert (q pre-scaled by 0.125)
    rope_kernel<<<10240, 256, 0, stream>>>(qkvp, wq_b, wk_b, wv_b, qr, kr, vbf);
    // 4) attention -> attb bf16 [1024][4096]
    attn_kernel<<<dim3(64, 16), 256, 0, stream>>>(qr, kr, vbf, sinks, attb);
    // 5) output projection, split-K=5 -> 5 bf16 partials [1024][2880]
    //    tiles: 12 N (last ragged: 64 valid cols) x 4 M = 48 blocks/z
    gemm8p<<<dim3(48, 1, 5), 512, 0, stream>>>(attb, 4096, 64, 6,
        wob, 12, 2880, 0,
        wob, 0, 0, 0,
        wob, 0, 0, 0,
        oprt, 2880, 1024LL * 2880);
    // 6) reduce partials + bias -> d_out fp32 [1024][2880]
    reduce_out_kernel<<<1440, 256, 0, stream>>>(oprt, wo_b, (float*)d_out);
}